// Round 1
// baseline (3332.837 us; speedup 1.0000x reference)
//
#include <hip/hip_runtime.h>
#include <hip/hip_bf16.h>

static constexpr int FDIM = 128;

// ---------------- norm precompute ----------------

__global__ __launch_bounds__(256) void k_init(float* __restrict__ deg,
                                              float* __restrict__ colsum,
                                              float* __restrict__ colmax,
                                              int n) {
    int i = blockIdx.x * 256 + threadIdx.x;
    if (i < n) deg[i] = 1.0f;                       // self-loop contributes 1
    if (i < FDIM) { colsum[i] = 0.0f; colmax[i] = 0.0f; }
}

__global__ __launch_bounds__(256) void k_degree(const int* __restrict__ dst,
                                                float* __restrict__ deg, int ne) {
    int i = blockIdx.x * 256 + threadIdx.x;
    if (i < ne) unsafeAtomicAdd(&deg[dst[i]], 1.0f);
}

__global__ __launch_bounds__(256) void k_rsqrt(float* __restrict__ deg, int n) {
    int i = blockIdx.x * 256 + threadIdx.x;
    if (i < n) deg[i] = 1.0f / sqrtf(deg[i]);       // deg >= 1 always
}

// ---------------- dense transform: H = X @ W  (K = 128) ----------------
// W (128x128 fp32 = 64 KB) staged in LDS once per block. Each thread owns
// one output column for 4 rows; X loads are wave-uniform float4 (broadcast).

__global__ __launch_bounds__(256) void k_gemm128(const float* __restrict__ X,
                                                 const float* __restrict__ W,
                                                 float* __restrict__ H, int n) {
    __shared__ float sW[FDIM * FDIM];
    for (int i = threadIdx.x; i < FDIM * FDIM / 4; i += 256)
        ((float4*)sW)[i] = ((const float4*)W)[i];
    __syncthreads();

    const int c = threadIdx.x & 127;
    const int half = threadIdx.x >> 7;   // 0 or 1
    for (int base = blockIdx.x * 8; base < n; base += gridDim.x * 8) {
        const int r0 = base + half * 4;
        const float* xp0 = X + (size_t)min(r0 + 0, n - 1) * FDIM;
        const float* xp1 = X + (size_t)min(r0 + 1, n - 1) * FDIM;
        const float* xp2 = X + (size_t)min(r0 + 2, n - 1) * FDIM;
        const float* xp3 = X + (size_t)min(r0 + 3, n - 1) * FDIM;
        float a0 = 0.f, a1 = 0.f, a2 = 0.f, a3 = 0.f;
#pragma unroll 8
        for (int k = 0; k < FDIM; k += 4) {
            float w0 = sW[(k + 0) * FDIM + c];
            float w1 = sW[(k + 1) * FDIM + c];
            float w2 = sW[(k + 2) * FDIM + c];
            float w3 = sW[(k + 3) * FDIM + c];
            float4 x0 = *(const float4*)(xp0 + k);
            float4 x1 = *(const float4*)(xp1 + k);
            float4 x2 = *(const float4*)(xp2 + k);
            float4 x3 = *(const float4*)(xp3 + k);
            a0 += x0.x * w0 + x0.y * w1 + x0.z * w2 + x0.w * w3;
            a1 += x1.x * w0 + x1.y * w1 + x1.z * w2 + x1.w * w3;
            a2 += x2.x * w0 + x2.y * w1 + x2.z * w2 + x2.w * w3;
            a3 += x3.x * w0 + x3.y * w1 + x3.z * w2 + x3.w * w3;
        }
        if (r0 + 0 < n) H[(size_t)(r0 + 0) * FDIM + c] = a0;
        if (r0 + 1 < n) H[(size_t)(r0 + 1) * FDIM + c] = a1;
        if (r0 + 2 < n) H[(size_t)(r0 + 2) * FDIM + c] = a2;
        if (r0 + 3 < n) H[(size_t)(r0 + 3) * FDIM + c] = a3;
    }
}

// ---------------- self-loop init: acc[i] = h[i] * dinv[i]^2 ----------------

__global__ __launch_bounds__(256) void k_selfinit(const float* __restrict__ H,
                                                  const float* __restrict__ dinv,
                                                  float* __restrict__ acc, int n) {
    int i = blockIdx.x * 256 + threadIdx.x;          // over n*32 float4s
    if (i >= n * 32) return;
    int row = i >> 5;
    float s = dinv[row];
    s *= s;
    float4 v = ((const float4*)H)[i];
    v.x *= s; v.y *= s; v.z *= s; v.w *= s;
    ((float4*)acc)[i] = v;
}

// ---------------- edge scatter: acc[dst] += h[src] * dinv[s]*dinv[d] -------
// One wave (64 lanes) per edge; float2 per lane covers the 128 channels.

__global__ __launch_bounds__(256) void k_scatter(const int* __restrict__ src,
                                                 const int* __restrict__ dst,
                                                 const float* __restrict__ dinv,
                                                 const float* __restrict__ H,
                                                 float* __restrict__ acc, int ne) {
    int e = (blockIdx.x * 256 + threadIdx.x) >> 6;
    if (e >= ne) return;
    int lane = threadIdx.x & 63;
    int s = src[e], d = dst[e];
    float w = dinv[s] * dinv[d];
    float2 v = ((const float2*)(H + (size_t)s * FDIM))[lane];
    float* ap = acc + (size_t)d * FDIM + lane * 2;
    unsafeAtomicAdd(ap, v.x * w);
    unsafeAtomicAdd(ap + 1, v.y * w);
}

// ---------------- bias + relu (in place) ----------------

__global__ __launch_bounds__(256) void k_bias_relu(float* __restrict__ acc,
                                                   const float* __restrict__ b,
                                                   int n) {
    int i = blockIdx.x * 256 + threadIdx.x;          // over n*32 float4s
    if (i >= n * 32) return;
    float4 bb = ((const float4*)b)[i & 31];
    float4 v = ((float4*)acc)[i];
    v.x = fmaxf(v.x + bb.x, 0.f);
    v.y = fmaxf(v.y + bb.y, 0.f);
    v.z = fmaxf(v.z + bb.z, 0.f);
    v.w = fmaxf(v.w + bb.w, 0.f);
    ((float4*)acc)[i] = v;
}

// ---------------- global mean+max pool ----------------
// relu output >= 0, so int atomicMax on float bits is order-preserving.

__global__ __launch_bounds__(256) void k_pool(const float* __restrict__ X,
                                              float* __restrict__ colsum,
                                              float* __restrict__ colmax, int n) {
    __shared__ float ls[256], lm[256];
    int c = threadIdx.x & 127;
    int grp = threadIdx.x >> 7;
    float s = 0.f, m = 0.f;
    for (int r = blockIdx.x * 2 + grp; r < n; r += gridDim.x * 2) {
        float v = X[(size_t)r * FDIM + c];
        s += v;
        m = fmaxf(m, v);
    }
    ls[threadIdx.x] = s;
    lm[threadIdx.x] = m;
    __syncthreads();
    if (threadIdx.x < 128) {
        s = ls[threadIdx.x] + ls[threadIdx.x + 128];
        m = fmaxf(lm[threadIdx.x], lm[threadIdx.x + 128]);
        unsafeAtomicAdd(&colsum[c], s);
        atomicMax((int*)colmax + c, __float_as_int(m));
    }
}

// ---------------- final FC: out = [mean, max] @ fcW + fcb ----------------

__global__ __launch_bounds__(256) void k_fc(const float* __restrict__ colsum,
                                            const float* __restrict__ colmax,
                                            const float* __restrict__ fcW,
                                            const float* __restrict__ fcb,
                                            float* __restrict__ out, float invN) {
    int o = threadIdx.x;   // 256 outputs
    float acc = fcb[o];
#pragma unroll 4
    for (int k = 0; k < FDIM; k++)
        acc += colsum[k] * invN * fcW[k * 256 + o];
#pragma unroll 4
    for (int k = 0; k < FDIM; k++)
        acc += colmax[k] * fcW[(FDIM + k) * 256 + o];
    out[o] = acc;
}

extern "C" void kernel_launch(void* const* d_in, const int* in_sizes, int n_in,
                              void* d_out, int out_size, void* d_ws, size_t ws_size,
                              hipStream_t stream) {
    const float* X   = (const float*)d_in[0];
    const int*   ei  = (const int*)d_in[1];
    const float* W1  = (const float*)d_in[2];
    const float* b1  = (const float*)d_in[3];
    const float* W2  = (const float*)d_in[4];
    const float* b2  = (const float*)d_in[5];
    const float* fcW = (const float*)d_in[6];
    const float* fcb = (const float*)d_in[7];
    float* out = (float*)d_out;

    const int n  = in_sizes[0] / FDIM;    // 100000
    const int ne = in_sizes[1] / 2;       // 1600000
    const int* src = ei;                  // edge_index[0]
    const int* dst = ei + ne;             // edge_index[1]

    // workspace carve: h[N*128] | acc[N*128] | dinv[N] | colsum[128] | colmax[128]
    float* h      = (float*)d_ws;
    float* acc    = h + (size_t)n * FDIM;
    float* dinv   = acc + (size_t)n * FDIM;
    float* colsum = dinv + n;
    float* colmax = colsum + FDIM;

    const int gN = (n + 255) / 256;
    const int gE = (ne + 255) / 256;
    const int gV = (n * 32 + 255) / 256;          // n*128 floats as float4
    const int gS = (int)(((long long)ne * 64 + 255) / 256);  // 1 wave per edge

    k_init<<<gN, 256, 0, stream>>>(dinv, colsum, colmax, n);
    k_degree<<<gE, 256, 0, stream>>>(dst, dinv, ne);
    k_rsqrt<<<gN, 256, 0, stream>>>(dinv, n);

    // layer 1
    k_gemm128<<<1024, 256, 0, stream>>>(X, W1, h, n);
    k_selfinit<<<gV, 256, 0, stream>>>(h, dinv, acc, n);
    k_scatter<<<gS, 256, 0, stream>>>(src, dst, dinv, h, acc, ne);
    k_bias_relu<<<gV, 256, 0, stream>>>(acc, b1, n);

    // layer 2 (acc == x1 feeds the GEMM, then is re-initialized after)
    k_gemm128<<<1024, 256, 0, stream>>>(acc, W2, h, n);
    k_selfinit<<<gV, 256, 0, stream>>>(h, dinv, acc, n);
    k_scatter<<<gS, 256, 0, stream>>>(src, dst, dinv, h, acc, ne);
    k_bias_relu<<<gV, 256, 0, stream>>>(acc, b2, n);

    // pool + fc
    k_pool<<<1024, 256, 0, stream>>>(acc, colsum, colmax, n);
    k_fc<<<1, 256, 0, stream>>>(colsum, colmax, fcW, fcb, out, 1.0f / (float)n);
}

// Round 2
// 1093.161 us; speedup vs baseline: 3.0488x; 3.0488x over previous
//
#include <hip/hip_runtime.h>
#include <hip/hip_bf16.h>

static constexpr int FDIM = 128;

// ================= shared small kernels =================

__global__ __launch_bounds__(256) void k_zero_init(int* __restrict__ counts,
                                                   float* __restrict__ colsum,
                                                   float* __restrict__ colmax,
                                                   int n) {
    int i = blockIdx.x * 256 + threadIdx.x;
    if (i < n) counts[i] = 0;
    if (i < FDIM) { colsum[i] = 0.0f; colmax[i] = 0.0f; }
}

__global__ __launch_bounds__(256) void k_hist(const int* __restrict__ dst,
                                              int* __restrict__ counts, int ne) {
    int i = blockIdx.x * 256 + threadIdx.x;
    if (i < ne) atomicAdd(&counts[dst[i]], 1);
}

__global__ __launch_bounds__(256) void k_dinv(const int* __restrict__ counts,
                                              float* __restrict__ dinv, int n) {
    int i = blockIdx.x * 256 + threadIdx.x;
    if (i < n) dinv[i] = 1.0f / sqrtf(1.0f + (float)counts[i]);  // +1 self loop
}

// ---------- exclusive scan (3-pass), n <= 512*256 ----------

__global__ __launch_bounds__(256) void k_scan1(const int* __restrict__ counts,
                                               int* __restrict__ work,
                                               int* __restrict__ partials, int n) {
    __shared__ int tmp[256];
    int i = blockIdx.x * 256 + threadIdx.x;
    int v = (i < n) ? counts[i] : 0;
    tmp[threadIdx.x] = v;
    __syncthreads();
    for (int off = 1; off < 256; off <<= 1) {
        int t = (threadIdx.x >= off) ? tmp[threadIdx.x - off] : 0;
        __syncthreads();
        tmp[threadIdx.x] += t;
        __syncthreads();
    }
    if (i < n) work[i] = tmp[threadIdx.x] - v;           // exclusive
    if (threadIdx.x == 255) partials[blockIdx.x] = tmp[255];
}

__global__ __launch_bounds__(512) void k_scan2(int* __restrict__ partials, int nb) {
    __shared__ int tmp[512];
    int v = (threadIdx.x < nb) ? partials[threadIdx.x] : 0;
    tmp[threadIdx.x] = v;
    __syncthreads();
    for (int off = 1; off < 512; off <<= 1) {
        int t = (threadIdx.x >= off) ? tmp[threadIdx.x - off] : 0;
        __syncthreads();
        tmp[threadIdx.x] += t;
        __syncthreads();
    }
    if (threadIdx.x < nb) partials[threadIdx.x] = tmp[threadIdx.x] - v;  // exclusive
}

__global__ __launch_bounds__(256) void k_scan3(int* __restrict__ work,
                                               const int* __restrict__ partials, int n) {
    int i = blockIdx.x * 256 + threadIdx.x;
    if (i < n) work[i] += partials[blockIdx.x];
}

// ---------- CSR fill: after this, work[d] == rowptr[d+1] ----------

__global__ __launch_bounds__(256) void k_fill(const int* __restrict__ src,
                                              const int* __restrict__ dst,
                                              int* __restrict__ work,
                                              int* __restrict__ csr, int ne) {
    int e = blockIdx.x * 256 + threadIdx.x;
    if (e < ne) {
        int pos = atomicAdd(&work[dst[e]], 1);
        csr[pos] = src[e];
    }
}

// ---------- dense transform with fused dinv scale: hs = dinv[r] * (X @ W) ----------

__global__ __launch_bounds__(256) void k_gemm128(const float* __restrict__ X,
                                                 const float* __restrict__ W,
                                                 const float* __restrict__ dinv,
                                                 float* __restrict__ H, int n) {
    __shared__ float sW[FDIM * FDIM];
    for (int i = threadIdx.x; i < FDIM * FDIM / 4; i += 256)
        ((float4*)sW)[i] = ((const float4*)W)[i];
    __syncthreads();

    const int c = threadIdx.x & 127;
    const int half = threadIdx.x >> 7;
    for (int base = blockIdx.x * 8; base < n; base += gridDim.x * 8) {
        const int r0 = base + half * 4;
        const float* xp0 = X + (size_t)min(r0 + 0, n - 1) * FDIM;
        const float* xp1 = X + (size_t)min(r0 + 1, n - 1) * FDIM;
        const float* xp2 = X + (size_t)min(r0 + 2, n - 1) * FDIM;
        const float* xp3 = X + (size_t)min(r0 + 3, n - 1) * FDIM;
        float a0 = 0.f, a1 = 0.f, a2 = 0.f, a3 = 0.f;
#pragma unroll 8
        for (int k = 0; k < FDIM; k += 4) {
            float w0 = sW[(k + 0) * FDIM + c];
            float w1 = sW[(k + 1) * FDIM + c];
            float w2 = sW[(k + 2) * FDIM + c];
            float w3 = sW[(k + 3) * FDIM + c];
            float4 x0 = *(const float4*)(xp0 + k);
            float4 x1 = *(const float4*)(xp1 + k);
            float4 x2 = *(const float4*)(xp2 + k);
            float4 x3 = *(const float4*)(xp3 + k);
            a0 += x0.x * w0 + x0.y * w1 + x0.z * w2 + x0.w * w3;
            a1 += x1.x * w0 + x1.y * w1 + x1.z * w2 + x1.w * w3;
            a2 += x2.x * w0 + x2.y * w1 + x2.z * w2 + x2.w * w3;
            a3 += x3.x * w0 + x3.y * w1 + x3.z * w2 + x3.w * w3;
        }
        if (r0 + 0 < n) H[(size_t)(r0 + 0) * FDIM + c] = a0 * dinv[r0 + 0];
        if (r0 + 1 < n) H[(size_t)(r0 + 1) * FDIM + c] = a1 * dinv[r0 + 1];
        if (r0 + 2 < n) H[(size_t)(r0 + 2) * FDIM + c] = a2 * dinv[r0 + 2];
        if (r0 + 3 < n) H[(size_t)(r0 + 3) * FDIM + c] = a3 * dinv[r0 + 3];
    }
}

// ---------- gather aggregate: out[d] = relu(dinv[d]*(hs[d] + sum hs[src]) + b) ----------
// One wave per destination node; 64 lanes x float2 = 128 channels.
// Edge indices loaded 64-wide then broadcast via shuffle (one vector load per
// 64 edges instead of 64 scalar broadcasts).

__global__ __launch_bounds__(256) void k_aggregate(const int* __restrict__ work,
                                                   const int* __restrict__ csr,
                                                   const float* __restrict__ dinv,
                                                   const float* __restrict__ hs,
                                                   const float* __restrict__ bias,
                                                   float* __restrict__ out, int n) {
    const int lane = threadIdx.x & 63;
    const int nwaves = gridDim.x * 4;
    int wid = (blockIdx.x * 256 + threadIdx.x) >> 6;
    const float2* hs2 = (const float2*)hs;
    const float2 bb = ((const float2*)bias)[lane];

    for (int node = wid; node < n; node += nwaves) {
        int beg = (node > 0) ? work[node - 1] : 0;
        int end = work[node];
        float2 a = hs2[(size_t)node * 64 + lane];        // self-loop term
        for (int chunk = beg; chunk < end; chunk += 64) {
            int m = end - chunk; if (m > 64) m = 64;
            int myidx = (lane < m) ? csr[chunk + lane] : 0;
            for (int j = 0; j < m; j++) {
                int s = __shfl(myidx, j);
                float2 v = hs2[(size_t)s * 64 + lane];
                a.x += v.x; a.y += v.y;
            }
        }
        float dd = dinv[node];
        float2 o;
        o.x = fmaxf(a.x * dd + bb.x, 0.f);
        o.y = fmaxf(a.y * dd + bb.y, 0.f);
        ((float2*)out)[(size_t)node * 64 + lane] = o;
    }
}

// ---------- global mean+max pool (relu out >= 0 -> int atomicMax valid) ----------

__global__ __launch_bounds__(256) void k_pool(const float* __restrict__ X,
                                              float* __restrict__ colsum,
                                              float* __restrict__ colmax, int n) {
    __shared__ float ls[256], lm[256];
    int c = threadIdx.x & 127;
    int grp = threadIdx.x >> 7;
    float s = 0.f, m = 0.f;
    for (int r = blockIdx.x * 2 + grp; r < n; r += gridDim.x * 2) {
        float v = X[(size_t)r * FDIM + c];
        s += v;
        m = fmaxf(m, v);
    }
    ls[threadIdx.x] = s;
    lm[threadIdx.x] = m;
    __syncthreads();
    if (threadIdx.x < 128) {
        s = ls[threadIdx.x] + ls[threadIdx.x + 128];
        m = fmaxf(lm[threadIdx.x], lm[threadIdx.x + 128]);
        unsafeAtomicAdd(&colsum[c], s);
        atomicMax((int*)colmax + c, __float_as_int(m));
    }
}

__global__ __launch_bounds__(256) void k_fc(const float* __restrict__ colsum,
                                            const float* __restrict__ colmax,
                                            const float* __restrict__ fcW,
                                            const float* __restrict__ fcb,
                                            float* __restrict__ out, float invN) {
    int o = threadIdx.x;
    float acc = fcb[o];
#pragma unroll 4
    for (int k = 0; k < FDIM; k++)
        acc += colsum[k] * invN * fcW[k * 256 + o];
#pragma unroll 4
    for (int k = 0; k < FDIM; k++)
        acc += colmax[k] * fcW[(FDIM + k) * 256 + o];
    out[o] = acc;
}

// ================= fallback (round-1 atomic scatter) =================

__global__ __launch_bounds__(256) void k_initF(float* deg, float* cs, float* cm, int n) {
    int i = blockIdx.x * 256 + threadIdx.x;
    if (i < n) deg[i] = 1.0f;
    if (i < FDIM) { cs[i] = 0.0f; cm[i] = 0.0f; }
}
__global__ __launch_bounds__(256) void k_degreeF(const int* dst, float* deg, int ne) {
    int i = blockIdx.x * 256 + threadIdx.x;
    if (i < ne) unsafeAtomicAdd(&deg[dst[i]], 1.0f);
}
__global__ __launch_bounds__(256) void k_rsqrtF(float* deg, int n) {
    int i = blockIdx.x * 256 + threadIdx.x;
    if (i < n) deg[i] = 1.0f / sqrtf(deg[i]);
}
__global__ __launch_bounds__(256) void k_selfinitF(const float* H, const float* dinv,
                                                   float* acc, int n) {
    int i = blockIdx.x * 256 + threadIdx.x;
    if (i >= n * 32) return;
    int row = i >> 5;
    float s = dinv[row]; s *= s;
    float4 v = ((const float4*)H)[i];
    v.x *= s; v.y *= s; v.z *= s; v.w *= s;
    ((float4*)acc)[i] = v;
}
__global__ __launch_bounds__(256) void k_scatterF(const int* src, const int* dst,
                                                  const float* dinv, const float* H,
                                                  float* acc, int ne) {
    int e = (blockIdx.x * 256 + threadIdx.x) >> 6;
    if (e >= ne) return;
    int lane = threadIdx.x & 63;
    int s = src[e], d = dst[e];
    float w = dinv[s] * dinv[d];
    float2 v = ((const float2*)(H + (size_t)s * FDIM))[lane];
    float* ap = acc + (size_t)d * FDIM + lane * 2;
    unsafeAtomicAdd(ap, v.x * w);
    unsafeAtomicAdd(ap + 1, v.y * w);
}
__global__ __launch_bounds__(256) void k_bias_reluF(float* acc, const float* b, int n) {
    int i = blockIdx.x * 256 + threadIdx.x;
    if (i >= n * 32) return;
    float4 bb = ((const float4*)b)[i & 31];
    float4 v = ((float4*)acc)[i];
    v.x = fmaxf(v.x + bb.x, 0.f);
    v.y = fmaxf(v.y + bb.y, 0.f);
    v.z = fmaxf(v.z + bb.z, 0.f);
    v.w = fmaxf(v.w + bb.w, 0.f);
    ((float4*)acc)[i] = v;
}
__global__ __launch_bounds__(256) void k_gemm128F(const float* X, const float* W,
                                                   float* H, int n) {
    __shared__ float sW[FDIM * FDIM];
    for (int i = threadIdx.x; i < FDIM * FDIM / 4; i += 256)
        ((float4*)sW)[i] = ((const float4*)W)[i];
    __syncthreads();
    const int c = threadIdx.x & 127;
    const int half = threadIdx.x >> 7;
    for (int base = blockIdx.x * 8; base < n; base += gridDim.x * 8) {
        const int r0 = base + half * 4;
        const float* xp0 = X + (size_t)min(r0 + 0, n - 1) * FDIM;
        const float* xp1 = X + (size_t)min(r0 + 1, n - 1) * FDIM;
        const float* xp2 = X + (size_t)min(r0 + 2, n - 1) * FDIM;
        const float* xp3 = X + (size_t)min(r0 + 3, n - 1) * FDIM;
        float a0 = 0.f, a1 = 0.f, a2 = 0.f, a3 = 0.f;
#pragma unroll 8
        for (int k = 0; k < FDIM; k += 4) {
            float w0 = sW[(k + 0) * FDIM + c];
            float w1 = sW[(k + 1) * FDIM + c];
            float w2 = sW[(k + 2) * FDIM + c];
            float w3 = sW[(k + 3) * FDIM + c];
            float4 x0 = *(const float4*)(xp0 + k);
            float4 x1 = *(const float4*)(xp1 + k);
            float4 x2 = *(const float4*)(xp2 + k);
            float4 x3 = *(const float4*)(xp3 + k);
            a0 += x0.x * w0 + x0.y * w1 + x0.z * w2 + x0.w * w3;
            a1 += x1.x * w0 + x1.y * w1 + x1.z * w2 + x1.w * w3;
            a2 += x2.x * w0 + x2.y * w1 + x2.z * w2 + x2.w * w3;
            a3 += x3.x * w0 + x3.y * w1 + x3.z * w2 + x3.w * w3;
        }
        if (r0 + 0 < n) H[(size_t)(r0 + 0) * FDIM + c] = a0;
        if (r0 + 1 < n) H[(size_t)(r0 + 1) * FDIM + c] = a1;
        if (r0 + 2 < n) H[(size_t)(r0 + 2) * FDIM + c] = a2;
        if (r0 + 3 < n) H[(size_t)(r0 + 3) * FDIM + c] = a3;
    }
}

// ================= launch =================

extern "C" void kernel_launch(void* const* d_in, const int* in_sizes, int n_in,
                              void* d_out, int out_size, void* d_ws, size_t ws_size,
                              hipStream_t stream) {
    const float* X   = (const float*)d_in[0];
    const int*   ei  = (const int*)d_in[1];
    const float* W1  = (const float*)d_in[2];
    const float* b1  = (const float*)d_in[3];
    const float* W2  = (const float*)d_in[4];
    const float* b2  = (const float*)d_in[5];
    const float* fcW = (const float*)d_in[6];
    const float* fcb = (const float*)d_in[7];
    float* out = (float*)d_out;

    const int n  = in_sizes[0] / FDIM;    // 100000
    const int ne = in_sizes[1] / 2;       // 1600000
    const int* src = ei;
    const int* dst = ei + ne;

    const int gN = (n + 255) / 256;
    const int gE = (ne + 255) / 256;

    // CSR-path workspace: hs | x | dinv (floats), counts | work | partials | csr (ints)
    size_t need = ((size_t)n * FDIM * 2 + n) * 4 + ((size_t)n * 2 + 512 + ne) * 4;

    if (ws_size >= need && gN <= 512) {
        float* hs     = (float*)d_ws;
        float* xbuf   = hs + (size_t)n * FDIM;
        float* dinv   = xbuf + (size_t)n * FDIM;
        float* colsum = dinv + n;             // reuse tail of float region
        float* colmax = colsum + FDIM;
        int* counts   = (int*)(dinv + n + 2 * FDIM);
        int* work     = counts + n;
        int* partials = work + n;
        int* csr      = partials + 512;

        k_zero_init<<<gN, 256, 0, stream>>>(counts, colsum, colmax, n);
        k_hist<<<gE, 256, 0, stream>>>(dst, counts, ne);
        k_dinv<<<gN, 256, 0, stream>>>(counts, dinv, n);
        k_scan1<<<gN, 256, 0, stream>>>(counts, work, partials, n);
        k_scan2<<<1, 512, 0, stream>>>(partials, gN);
        k_scan3<<<gN, 256, 0, stream>>>(work, partials, n);
        k_fill<<<gE, 256, 0, stream>>>(src, dst, work, csr, ne);

        // layer 1
        k_gemm128<<<1024, 256, 0, stream>>>(X, W1, dinv, hs, n);
        k_aggregate<<<2048, 256, 0, stream>>>(work, csr, dinv, hs, b1, xbuf, n);
        // layer 2
        k_gemm128<<<1024, 256, 0, stream>>>(xbuf, W2, dinv, hs, n);
        k_aggregate<<<2048, 256, 0, stream>>>(work, csr, dinv, hs, b2, xbuf, n);

        k_pool<<<1024, 256, 0, stream>>>(xbuf, colsum, colmax, n);
        k_fc<<<1, 256, 0, stream>>>(colsum, colmax, fcW, fcb, out, 1.0f / (float)n);
    } else {
        // fallback: round-1 atomic-scatter path (needs 2*N*128 + N + 256 floats)
        float* h      = (float*)d_ws;
        float* acc    = h + (size_t)n * FDIM;
        float* dinv   = acc + (size_t)n * FDIM;
        float* colsum = dinv + n;
        float* colmax = colsum + FDIM;
        const int gV = (n * 32 + 255) / 256;
        const int gS = (int)(((long long)ne * 64 + 255) / 256);

        k_initF<<<gN, 256, 0, stream>>>(dinv, colsum, colmax, n);
        k_degreeF<<<gE, 256, 0, stream>>>(dst, dinv, ne);
        k_rsqrtF<<<gN, 256, 0, stream>>>(dinv, n);

        k_gemm128F<<<1024, 256, 0, stream>>>(X, W1, h, n);
        k_selfinitF<<<gV, 256, 0, stream>>>(h, dinv, acc, n);
        k_scatterF<<<gS, 256, 0, stream>>>(src, dst, dinv, h, acc, ne);
        k_bias_reluF<<<gV, 256, 0, stream>>>(acc, b1, n);

        k_gemm128F<<<1024, 256, 0, stream>>>(acc, W2, h, n);
        k_selfinitF<<<gV, 256, 0, stream>>>(h, dinv, acc, n);
        k_scatterF<<<gS, 256, 0, stream>>>(src, dst, dinv, h, acc, ne);
        k_bias_reluF<<<gV, 256, 0, stream>>>(acc, b2, n);

        k_pool<<<1024, 256, 0, stream>>>(acc, colsum, colmax, n);
        k_fc<<<1, 256, 0, stream>>>(colsum, colmax, fcW, fcb, out, 1.0f / (float)n);
    }
}

// Round 3
// 733.220 us; speedup vs baseline: 4.5455x; 1.4909x over previous
//
#include <hip/hip_runtime.h>
#include <hip/hip_bf16.h>

static constexpr int FDIM = 128;

// ================= shared small kernels =================

__global__ __launch_bounds__(256) void k_zero_init(int* __restrict__ counts,
                                                   float* __restrict__ colsum,
                                                   float* __restrict__ colmax,
                                                   int n) {
    int i = blockIdx.x * 256 + threadIdx.x;
    if (i < n) counts[i] = 0;
    if (i < FDIM) { colsum[i] = 0.0f; colmax[i] = 0.0f; }
}

__global__ __launch_bounds__(256) void k_hist(const int* __restrict__ dst,
                                              int* __restrict__ counts, int ne) {
    int i = blockIdx.x * 256 + threadIdx.x;
    if (i < ne) atomicAdd(&counts[dst[i]], 1);
}

__global__ __launch_bounds__(256) void k_dinv(const int* __restrict__ counts,
                                              float* __restrict__ dinv, int n) {
    int i = blockIdx.x * 256 + threadIdx.x;
    if (i < n) dinv[i] = 1.0f / sqrtf(1.0f + (float)counts[i]);  // +1 self loop
}

// ---------- exclusive scan (3-pass), n <= 512*256 ----------

__global__ __launch_bounds__(256) void k_scan1(const int* __restrict__ counts,
                                               int* __restrict__ work,
                                               int* __restrict__ partials, int n) {
    __shared__ int tmp[256];
    int i = blockIdx.x * 256 + threadIdx.x;
    int v = (i < n) ? counts[i] : 0;
    tmp[threadIdx.x] = v;
    __syncthreads();
    for (int off = 1; off < 256; off <<= 1) {
        int t = (threadIdx.x >= off) ? tmp[threadIdx.x - off] : 0;
        __syncthreads();
        tmp[threadIdx.x] += t;
        __syncthreads();
    }
    if (i < n) work[i] = tmp[threadIdx.x] - v;           // exclusive
    if (threadIdx.x == 255) partials[blockIdx.x] = tmp[255];
}

__global__ __launch_bounds__(512) void k_scan2(int* __restrict__ partials, int nb) {
    __shared__ int tmp[512];
    int v = (threadIdx.x < nb) ? partials[threadIdx.x] : 0;
    tmp[threadIdx.x] = v;
    __syncthreads();
    for (int off = 1; off < 512; off <<= 1) {
        int t = (threadIdx.x >= off) ? tmp[threadIdx.x - off] : 0;
        __syncthreads();
        tmp[threadIdx.x] += t;
        __syncthreads();
    }
    if (threadIdx.x < nb) partials[threadIdx.x] = tmp[threadIdx.x] - v;  // exclusive
}

__global__ __launch_bounds__(256) void k_scan3(int* __restrict__ work,
                                               const int* __restrict__ partials, int n) {
    int i = blockIdx.x * 256 + threadIdx.x;
    if (i < n) work[i] += partials[blockIdx.x];
}

// ---------- CSR fill: after this, work[d] == rowptr[d+1] ----------

__global__ __launch_bounds__(256) void k_fill(const int* __restrict__ src,
                                              const int* __restrict__ dst,
                                              int* __restrict__ work,
                                              int* __restrict__ csr, int ne) {
    int e = blockIdx.x * 256 + threadIdx.x;
    if (e < ne) {
        int pos = atomicAdd(&work[dst[e]], 1);
        csr[pos] = src[e];
    }
}

// ---------- dense transform: hs = dinv[r] * (X @ W) ----------
// Block computes 64 rows x 64 cols (col half chosen by blockIdx parity).
// sX: 64x128 fp32, XOR-swizzled at float4 granularity so staging writes and
// b128 reads both spread across bank quads. sW: 128x64 col slice. 64 KB LDS
// total -> 2 blocks/CU. Thread tile 4x4; per 4-k step: 8 ds_read_b128 feed
// 64 FMAs (~75% FMA issue mix).

#define ACC4(A, XV)                                          \
    A.x += XV.x*w0.x + XV.y*w1.x + XV.z*w2.x + XV.w*w3.x;    \
    A.y += XV.x*w0.y + XV.y*w1.y + XV.z*w2.y + XV.w*w3.y;    \
    A.z += XV.x*w0.z + XV.y*w1.z + XV.z*w2.z + XV.w*w3.z;    \
    A.w += XV.x*w0.w + XV.y*w1.w + XV.z*w2.w + XV.w*w3.w;

__global__ __launch_bounds__(256) void k_gemm_tile(const float* __restrict__ X,
                                                   const float* __restrict__ W,
                                                   const float* __restrict__ dinv,
                                                   float* __restrict__ H, int n) {
    __shared__ float sX[64 * FDIM];      // 32 KB
    __shared__ float sW[FDIM * 64];      // 32 KB
    const int t = threadIdx.x;
    const int lane = t & 63;
    const int w = t >> 6;                // wave 0..3
    const int ci = lane & 7;
    const int ri = lane >> 3;
    const int half = blockIdx.x & 1;     // which 64-col slice of W
    const int r0 = (w >> 1) * 32 + ri * 4;        // row in tile (0..63)
    const int ccol = (w & 1) * 32 + ci * 4;       // col within slice (0..63)
    const int gc0 = half * 64 + ccol;             // global col

    // stage W col-slice once per block
    for (int i = 0; i < 8; i++) {
        int f = i * 256 + t;
        int wk = f >> 4, wc = f & 15;
        ((float4*)sW)[wk * 16 + wc] =
            ((const float4*)(W + (size_t)wk * FDIM + half * 64))[wc];
    }

    const int ntiles = (n + 63) >> 6;
    const int tstride = gridDim.x >> 1;
    for (int tile = blockIdx.x >> 1; tile < ntiles; tile += tstride) {
        const int R0 = tile * 64;
        __syncthreads();                 // prior k-loop readers done
        for (int i = 0; i < 8; i++) {
            int f = i * 256 + t;
            int row = f >> 5, c32 = f & 31;
            int gr = min(R0 + row, n - 1);
            float4 v = ((const float4*)(X + (size_t)gr * FDIM))[c32];
            ((float4*)sX)[row * 32 + ((c32 ^ (row >> 2)) & 31)] = v;
        }
        __syncthreads();

        float4 a0 = {0,0,0,0}, a1 = {0,0,0,0}, a2 = {0,0,0,0}, a3 = {0,0,0,0};
        const int g = r0 >> 2;           // swizzle group (same for r0..r0+3)
#pragma unroll 8
        for (int kb = 0; kb < 32; kb++) {
            int sw = (kb ^ g) & 31;
            float4 x0 = ((const float4*)sX)[(r0 + 0) * 32 + sw];
            float4 x1 = ((const float4*)sX)[(r0 + 1) * 32 + sw];
            float4 x2 = ((const float4*)sX)[(r0 + 2) * 32 + sw];
            float4 x3 = ((const float4*)sX)[(r0 + 3) * 32 + sw];
            float4 w0 = ((const float4*)sW)[(kb * 4 + 0) * 16 + (ccol >> 2)];
            float4 w1 = ((const float4*)sW)[(kb * 4 + 1) * 16 + (ccol >> 2)];
            float4 w2 = ((const float4*)sW)[(kb * 4 + 2) * 16 + (ccol >> 2)];
            float4 w3 = ((const float4*)sW)[(kb * 4 + 3) * 16 + (ccol >> 2)];
            ACC4(a0, x0) ACC4(a1, x1) ACC4(a2, x2) ACC4(a3, x3)
        }

        int r = R0 + r0;
        if (r + 0 < n) { float d = dinv[r + 0]; float4 o = a0;
            o.x *= d; o.y *= d; o.z *= d; o.w *= d;
            *(float4*)(H + (size_t)(r + 0) * FDIM + gc0) = o; }
        if (r + 1 < n) { float d = dinv[r + 1]; float4 o = a1;
            o.x *= d; o.y *= d; o.z *= d; o.w *= d;
            *(float4*)(H + (size_t)(r + 1) * FDIM + gc0) = o; }
        if (r + 2 < n) { float d = dinv[r + 2]; float4 o = a2;
            o.x *= d; o.y *= d; o.z *= d; o.w *= d;
            *(float4*)(H + (size_t)(r + 2) * FDIM + gc0) = o; }
        if (r + 3 < n) { float d = dinv[r + 3]; float4 o = a3;
            o.x *= d; o.y *= d; o.z *= d; o.w *= d;
            *(float4*)(H + (size_t)(r + 3) * FDIM + gc0) = o; }
    }
}

// ---------- gather aggregate: out[d] = relu(dinv[d]*(hs[d] + sum hs[src]) + b) ----------

__global__ __launch_bounds__(256) void k_aggregate(const int* __restrict__ work,
                                                   const int* __restrict__ csr,
                                                   const float* __restrict__ dinv,
                                                   const float* __restrict__ hs,
                                                   const float* __restrict__ bias,
                                                   float* __restrict__ out, int n) {
    const int lane = threadIdx.x & 63;
    const int nwaves = gridDim.x * 4;
    int wid = (blockIdx.x * 256 + threadIdx.x) >> 6;
    const float2* hs2 = (const float2*)hs;
    const float2 bb = ((const float2*)bias)[lane];

    for (int node = wid; node < n; node += nwaves) {
        int beg = (node > 0) ? work[node - 1] : 0;
        int end = work[node];
        float2 a = hs2[(size_t)node * 64 + lane];        // self-loop term
        for (int chunk = beg; chunk < end; chunk += 64) {
            int m = end - chunk; if (m > 64) m = 64;
            int myidx = (lane < m) ? csr[chunk + lane] : 0;
            for (int j = 0; j < m; j++) {
                int s = __shfl(myidx, j);
                float2 v = hs2[(size_t)s * 64 + lane];
                a.x += v.x; a.y += v.y;
            }
        }
        float dd = dinv[node];
        float2 o;
        o.x = fmaxf(a.x * dd + bb.x, 0.f);
        o.y = fmaxf(a.y * dd + bb.y, 0.f);
        ((float2*)out)[(size_t)node * 64 + lane] = o;
    }
}

// ---------- global mean+max pool (relu out >= 0 -> int atomicMax valid) ----------

__global__ __launch_bounds__(256) void k_pool(const float* __restrict__ X,
                                              float* __restrict__ colsum,
                                              float* __restrict__ colmax, int n) {
    __shared__ float ls[256], lm[256];
    int c = threadIdx.x & 127;
    int grp = threadIdx.x >> 7;
    float s = 0.f, m = 0.f;
    for (int r = blockIdx.x * 2 + grp; r < n; r += gridDim.x * 2) {
        float v = X[(size_t)r * FDIM + c];
        s += v;
        m = fmaxf(m, v);
    }
    ls[threadIdx.x] = s;
    lm[threadIdx.x] = m;
    __syncthreads();
    if (threadIdx.x < 128) {
        s = ls[threadIdx.x] + ls[threadIdx.x + 128];
        m = fmaxf(lm[threadIdx.x], lm[threadIdx.x + 128]);
        unsafeAtomicAdd(&colsum[c], s);
        atomicMax((int*)colmax + c, __float_as_int(m));
    }
}

__global__ __launch_bounds__(256) void k_fc(const float* __restrict__ colsum,
                                            const float* __restrict__ colmax,
                                            const float* __restrict__ fcW,
                                            const float* __restrict__ fcb,
                                            float* __restrict__ out, float invN) {
    int o = threadIdx.x;
    float acc = fcb[o];
#pragma unroll 4
    for (int k = 0; k < FDIM; k++)
        acc += colsum[k] * invN * fcW[k * 256 + o];
#pragma unroll 4
    for (int k = 0; k < FDIM; k++)
        acc += colmax[k] * fcW[(FDIM + k) * 256 + o];
    out[o] = acc;
}

// ================= fallback (round-1 atomic scatter) =================

__global__ __launch_bounds__(256) void k_initF(float* deg, float* cs, float* cm, int n) {
    int i = blockIdx.x * 256 + threadIdx.x;
    if (i < n) deg[i] = 1.0f;
    if (i < FDIM) { cs[i] = 0.0f; cm[i] = 0.0f; }
}
__global__ __launch_bounds__(256) void k_degreeF(const int* dst, float* deg, int ne) {
    int i = blockIdx.x * 256 + threadIdx.x;
    if (i < ne) unsafeAtomicAdd(&deg[dst[i]], 1.0f);
}
__global__ __launch_bounds__(256) void k_rsqrtF(float* deg, int n) {
    int i = blockIdx.x * 256 + threadIdx.x;
    if (i < n) deg[i] = 1.0f / sqrtf(deg[i]);
}
__global__ __launch_bounds__(256) void k_selfinitF(const float* H, const float* dinv,
                                                   float* acc, int n) {
    int i = blockIdx.x * 256 + threadIdx.x;
    if (i >= n * 32) return;
    int row = i >> 5;
    float s = dinv[row]; s *= s;
    float4 v = ((const float4*)H)[i];
    v.x *= s; v.y *= s; v.z *= s; v.w *= s;
    ((float4*)acc)[i] = v;
}
__global__ __launch_bounds__(256) void k_scatterF(const int* src, const int* dst,
                                                  const float* dinv, const float* H,
                                                  float* acc, int ne) {
    int e = (blockIdx.x * 256 + threadIdx.x) >> 6;
    if (e >= ne) return;
    int lane = threadIdx.x & 63;
    int s = src[e], d = dst[e];
    float w = dinv[s] * dinv[d];
    float2 v = ((const float2*)(H + (size_t)s * FDIM))[lane];
    float* ap = acc + (size_t)d * FDIM + lane * 2;
    unsafeAtomicAdd(ap, v.x * w);
    unsafeAtomicAdd(ap + 1, v.y * w);
}
__global__ __launch_bounds__(256) void k_bias_reluF(float* acc, const float* b, int n) {
    int i = blockIdx.x * 256 + threadIdx.x;
    if (i >= n * 32) return;
    float4 bb = ((const float4*)b)[i & 31];
    float4 v = ((float4*)acc)[i];
    v.x = fmaxf(v.x + bb.x, 0.f);
    v.y = fmaxf(v.y + bb.y, 0.f);
    v.z = fmaxf(v.z + bb.z, 0.f);
    v.w = fmaxf(v.w + bb.w, 0.f);
    ((float4*)acc)[i] = v;
}
__global__ __launch_bounds__(256) void k_gemm128F(const float* X, const float* W,
                                                   float* H, int n) {
    __shared__ float sW[FDIM * FDIM];
    for (int i = threadIdx.x; i < FDIM * FDIM / 4; i += 256)
        ((float4*)sW)[i] = ((const float4*)W)[i];
    __syncthreads();
    const int c = threadIdx.x & 127;
    const int half = threadIdx.x >> 7;
    for (int base = blockIdx.x * 8; base < n; base += gridDim.x * 8) {
        const int r0 = base + half * 4;
        const float* xp0 = X + (size_t)min(r0 + 0, n - 1) * FDIM;
        const float* xp1 = X + (size_t)min(r0 + 1, n - 1) * FDIM;
        const float* xp2 = X + (size_t)min(r0 + 2, n - 1) * FDIM;
        const float* xp3 = X + (size_t)min(r0 + 3, n - 1) * FDIM;
        float a0 = 0.f, a1 = 0.f, a2 = 0.f, a3 = 0.f;
#pragma unroll 8
        for (int k = 0; k < FDIM; k += 4) {
            float w0 = sW[(k + 0) * FDIM + c];
            float w1 = sW[(k + 1) * FDIM + c];
            float w2 = sW[(k + 2) * FDIM + c];
            float w3 = sW[(k + 3) * FDIM + c];
            float4 x0 = *(const float4*)(xp0 + k);
            float4 x1 = *(const float4*)(xp1 + k);
            float4 x2 = *(const float4*)(xp2 + k);
            float4 x3 = *(const float4*)(xp3 + k);
            a0 += x0.x * w0 + x0.y * w1 + x0.z * w2 + x0.w * w3;
            a1 += x1.x * w0 + x1.y * w1 + x1.z * w2 + x1.w * w3;
            a2 += x2.x * w0 + x2.y * w1 + x2.z * w2 + x2.w * w3;
            a3 += x3.x * w0 + x3.y * w1 + x3.z * w2 + x3.w * w3;
        }
        if (r0 + 0 < n) H[(size_t)(r0 + 0) * FDIM + c] = a0;
        if (r0 + 1 < n) H[(size_t)(r0 + 1) * FDIM + c] = a1;
        if (r0 + 2 < n) H[(size_t)(r0 + 2) * FDIM + c] = a2;
        if (r0 + 3 < n) H[(size_t)(r0 + 3) * FDIM + c] = a3;
    }
}

// ================= launch =================

extern "C" void kernel_launch(void* const* d_in, const int* in_sizes, int n_in,
                              void* d_out, int out_size, void* d_ws, size_t ws_size,
                              hipStream_t stream) {
    const float* X   = (const float*)d_in[0];
    const int*   ei  = (const int*)d_in[1];
    const float* W1  = (const float*)d_in[2];
    const float* b1  = (const float*)d_in[3];
    const float* W2  = (const float*)d_in[4];
    const float* b2  = (const float*)d_in[5];
    const float* fcW = (const float*)d_in[6];
    const float* fcb = (const float*)d_in[7];
    float* out = (float*)d_out;

    const int n  = in_sizes[0] / FDIM;    // 100000
    const int ne = in_sizes[1] / 2;       // 1600000
    const int* src = ei;
    const int* dst = ei + ne;

    const int gN = (n + 255) / 256;
    const int gE = (ne + 255) / 256;

    // CSR-path workspace: hs | x | dinv (floats), counts | work | partials | csr (ints)
    size_t need = ((size_t)n * FDIM * 2 + n) * 4 + ((size_t)n * 2 + 512 + ne) * 4;

    if (ws_size >= need && gN <= 512) {
        float* hs     = (float*)d_ws;
        float* xbuf   = hs + (size_t)n * FDIM;
        float* dinv   = xbuf + (size_t)n * FDIM;
        float* colsum = dinv + n;
        float* colmax = colsum + FDIM;
        int* counts   = (int*)(dinv + n + 2 * FDIM);
        int* work     = counts + n;
        int* partials = work + n;
        int* csr      = partials + 512;

        k_zero_init<<<gN, 256, 0, stream>>>(counts, colsum, colmax, n);
        k_hist<<<gE, 256, 0, stream>>>(dst, counts, ne);
        k_dinv<<<gN, 256, 0, stream>>>(counts, dinv, n);
        k_scan1<<<gN, 256, 0, stream>>>(counts, work, partials, n);
        k_scan2<<<1, 512, 0, stream>>>(partials, gN);
        k_scan3<<<gN, 256, 0, stream>>>(work, partials, n);
        k_fill<<<gE, 256, 0, stream>>>(src, dst, work, csr, ne);

        // layer 1
        k_gemm_tile<<<512, 256, 0, stream>>>(X, W1, dinv, hs, n);
        k_aggregate<<<2048, 256, 0, stream>>>(work, csr, dinv, hs, b1, xbuf, n);
        // layer 2
        k_gemm_tile<<<512, 256, 0, stream>>>(xbuf, W2, dinv, hs, n);
        k_aggregate<<<2048, 256, 0, stream>>>(work, csr, dinv, hs, b2, xbuf, n);

        k_pool<<<1024, 256, 0, stream>>>(xbuf, colsum, colmax, n);
        k_fc<<<1, 256, 0, stream>>>(colsum, colmax, fcW, fcb, out, 1.0f / (float)n);
    } else {
        // fallback: round-1 atomic-scatter path
        float* h      = (float*)d_ws;
        float* acc    = h + (size_t)n * FDIM;
        float* dinv   = acc + (size_t)n * FDIM;
        float* colsum = dinv + n;
        float* colmax = colsum + FDIM;
        const int gV = (n * 32 + 255) / 256;
        const int gS = (int)(((long long)ne * 64 + 255) / 256);

        k_initF<<<gN, 256, 0, stream>>>(dinv, colsum, colmax, n);
        k_degreeF<<<gE, 256, 0, stream>>>(dst, dinv, ne);
        k_rsqrtF<<<gN, 256, 0, stream>>>(dinv, n);

        k_gemm128F<<<1024, 256, 0, stream>>>(X, W1, h, n);
        k_selfinitF<<<gV, 256, 0, stream>>>(h, dinv, acc, n);
        k_scatterF<<<gS, 256, 0, stream>>>(src, dst, dinv, h, acc, ne);
        k_bias_reluF<<<gV, 256, 0, stream>>>(acc, b1, n);

        k_gemm128F<<<1024, 256, 0, stream>>>(acc, W2, h, n);
        k_selfinitF<<<gV, 256, 0, stream>>>(h, dinv, acc, n);
        k_scatterF<<<gS, 256, 0, stream>>>(src, dst, dinv, h, acc, ne);
        k_bias_reluF<<<gV, 256, 0, stream>>>(acc, b2, n);

        k_pool<<<1024, 256, 0, stream>>>(acc, colsum, colmax, n);
        k_fc<<<1, 256, 0, stream>>>(colsum, colmax, fcW, fcb, out, 1.0f / (float)n);
    }
}

// Round 4
// 591.529 us; speedup vs baseline: 5.6343x; 1.2395x over previous
//
#include <hip/hip_runtime.h>
#include <hip/hip_bf16.h>
#include <hip/hip_fp16.h>

static constexpr int FDIM = 128;

typedef _Float16 h8 __attribute__((ext_vector_type(8)));
typedef _Float16 h2 __attribute__((ext_vector_type(2)));
typedef float v4f __attribute__((ext_vector_type(4)));

// ================= shared small kernels =================

__global__ __launch_bounds__(256) void k_zero_init(int* __restrict__ counts,
                                                   float* __restrict__ colsum,
                                                   float* __restrict__ colmax,
                                                   int n) {
    int i = blockIdx.x * 256 + threadIdx.x;
    if (i < n) counts[i] = 0;
    if (i < FDIM) { colsum[i] = 0.0f; colmax[i] = 0.0f; }
}

__global__ __launch_bounds__(256) void k_hist(const int* __restrict__ dst,
                                              int* __restrict__ counts, int ne) {
    int i = blockIdx.x * 256 + threadIdx.x;
    if (i < ne) atomicAdd(&counts[dst[i]], 1);
}

__global__ __launch_bounds__(256) void k_dinv(const int* __restrict__ counts,
                                              float* __restrict__ dinv, int n) {
    int i = blockIdx.x * 256 + threadIdx.x;
    if (i < n) dinv[i] = 1.0f / sqrtf(1.0f + (float)counts[i]);  // +1 self loop
}

// ---------- exclusive scan (3-pass), n <= 512*256 ----------

__global__ __launch_bounds__(256) void k_scan1(const int* __restrict__ counts,
                                               int* __restrict__ work,
                                               int* __restrict__ partials, int n) {
    __shared__ int tmp[256];
    int i = blockIdx.x * 256 + threadIdx.x;
    int v = (i < n) ? counts[i] : 0;
    tmp[threadIdx.x] = v;
    __syncthreads();
    for (int off = 1; off < 256; off <<= 1) {
        int t = (threadIdx.x >= off) ? tmp[threadIdx.x - off] : 0;
        __syncthreads();
        tmp[threadIdx.x] += t;
        __syncthreads();
    }
    if (i < n) work[i] = tmp[threadIdx.x] - v;           // exclusive
    if (threadIdx.x == 255) partials[blockIdx.x] = tmp[255];
}

__global__ __launch_bounds__(512) void k_scan2(int* __restrict__ partials, int nb) {
    __shared__ int tmp[512];
    int v = (threadIdx.x < nb) ? partials[threadIdx.x] : 0;
    tmp[threadIdx.x] = v;
    __syncthreads();
    for (int off = 1; off < 512; off <<= 1) {
        int t = (threadIdx.x >= off) ? tmp[threadIdx.x - off] : 0;
        __syncthreads();
        tmp[threadIdx.x] += t;
        __syncthreads();
    }
    if (threadIdx.x < nb) partials[threadIdx.x] = tmp[threadIdx.x] - v;  // exclusive
}

__global__ __launch_bounds__(256) void k_scan3(int* __restrict__ work,
                                               const int* __restrict__ partials, int n) {
    int i = blockIdx.x * 256 + threadIdx.x;
    if (i < n) work[i] += partials[blockIdx.x];
}

// ---------- CSR fill: after this, work[d] == rowptr[d+1] ----------

__global__ __launch_bounds__(256) void k_fill(const int* __restrict__ src,
                                              const int* __restrict__ dst,
                                              int* __restrict__ work,
                                              int* __restrict__ csr, int ne) {
    int e = blockIdx.x * 256 + threadIdx.x;
    if (e < ne) {
        int pos = atomicAdd(&work[dst[e]], 1);
        csr[pos] = src[e];
    }
}

// ---------- W transpose + fp16 cast: T[n][k] = (fp16) W[k][n] ----------

__global__ __launch_bounds__(256) void k_transW(const float* __restrict__ W1,
                                                const float* __restrict__ W2,
                                                _Float16* __restrict__ T1,
                                                _Float16* __restrict__ T2) {
    int b = blockIdx.x;                       // 0..127
    const float* W = (b < 64) ? W1 : W2;
    _Float16* T = (b < 64) ? T1 : T2;
    int idx = (b & 63) * 256 + threadIdx.x;   // 0..16383
    int k = idx >> 7, nn = idx & 127;
    T[nn * FDIM + k] = (_Float16)W[idx];
}

// ---------- MFMA GEMM: H(fp16) = X @ W  (M x 128 x 128) ----------
// Block tile 128 rows x 128 cols; 4 waves each own a 64x64 quadrant
// (4x4 grid of 16x16x32 f16 MFMA tiles, K = 4 steps of 32).
// sA: X tile 128x128 fp16, 16 B granules XOR-swizzled by row (bank-spread).
// sB: W^T 128x128 fp16 (same swizzle by col), staged once per block.

template <typename T>
__global__ __launch_bounds__(256) void k_gemm_f16(const T* __restrict__ X,
                                                  const _Float16* __restrict__ WT,
                                                  _Float16* __restrict__ H, int n) {
    __shared__ _Float16 sA[FDIM * FDIM];   // 32 KB
    __shared__ _Float16 sB[FDIM * FDIM];   // 32 KB
    const int t = threadIdx.x;
    const int lane = t & 63;
    const int w = t >> 6;
    const int rowhalf = w >> 1, colhalf = w & 1;

    for (int i = 0; i < 8; i++) {          // stage W^T once
        int f = i * 256 + t;
        int nn = f >> 4, g = f & 15;
        ((float4*)sB)[nn * 16 + ((g ^ nn) & 15)] = ((const float4*)WT)[f];
    }

    const int ntiles = (n + 127) >> 7;
    for (int tile = blockIdx.x; tile < ntiles; tile += gridDim.x) {
        const int R0 = tile << 7;
        __syncthreads();                    // frag readers done / sB staged
        for (int i = 0; i < 8; i++) {
            int f = i * 256 + t;
            int row = f >> 4, g = f & 15;
            int gr = min(R0 + row, n - 1);
            h8 val;
            if constexpr (sizeof(T) == 4) {
                const float4* xp = (const float4*)(X + (size_t)gr * FDIM + g * 8);
                float4 u0 = xp[0], u1 = xp[1];
                val[0] = (_Float16)u0.x; val[1] = (_Float16)u0.y;
                val[2] = (_Float16)u0.z; val[3] = (_Float16)u0.w;
                val[4] = (_Float16)u1.x; val[5] = (_Float16)u1.y;
                val[6] = (_Float16)u1.z; val[7] = (_Float16)u1.w;
            } else {
                val = ((const h8*)(X + (size_t)gr * FDIM))[g];
            }
            ((h8*)sA)[row * 16 + ((g ^ row) & 15)] = val;
        }
        __syncthreads();

        v4f acc[4][4];
#pragma unroll
        for (int rt = 0; rt < 4; rt++)
#pragma unroll
            for (int ct = 0; ct < 4; ct++)
                acc[rt][ct] = (v4f){0.f, 0.f, 0.f, 0.f};

#pragma unroll
        for (int s = 0; s < 4; s++) {
            const int g0 = s * 4 + (lane >> 4);
            h8 af[4], bf[4];
#pragma unroll
            for (int rt = 0; rt < 4; rt++) {
                int row = rowhalf * 64 + rt * 16 + (lane & 15);
                af[rt] = ((const h8*)sA)[row * 16 + ((g0 ^ row) & 15)];
            }
#pragma unroll
            for (int ct = 0; ct < 4; ct++) {
                int nn = colhalf * 64 + ct * 16 + (lane & 15);
                bf[ct] = ((const h8*)sB)[nn * 16 + ((g0 ^ nn) & 15)];
            }
#pragma unroll
            for (int rt = 0; rt < 4; rt++)
#pragma unroll
                for (int ct = 0; ct < 4; ct++)
                    acc[rt][ct] = __builtin_amdgcn_mfma_f32_16x16x32_f16(
                        af[rt], bf[ct], acc[rt][ct], 0, 0, 0);
        }

        // epilogue: C/D layout col = lane&15, row = (lane>>4)*4 + reg
        const int rb = R0 + rowhalf * 64 + (lane >> 4) * 4;
        const int cb = colhalf * 64 + (lane & 15);
#pragma unroll
        for (int rt = 0; rt < 4; rt++)
#pragma unroll
            for (int reg = 0; reg < 4; reg++) {
                int grow = rb + rt * 16 + reg;
                if (grow < n) {
                    _Float16* hp = H + (size_t)grow * FDIM + cb;
#pragma unroll
                    for (int ct = 0; ct < 4; ct++)
                        hp[ct * 16] = (_Float16)acc[rt][ct][reg];
                }
            }
    }
}

// ---------- gather aggregate (fp16 messages, fp32 accumulate) ----------
// out[d] = relu(dinv[d]*(dinv[d]*h[d] + sum_s dinv[s]*h[s]) + b), fp16 out.

__global__ __launch_bounds__(256) void k_aggregate(const int* __restrict__ work,
                                                   const int* __restrict__ csr,
                                                   const float* __restrict__ dinv,
                                                   const _Float16* __restrict__ hs,
                                                   const float* __restrict__ bias,
                                                   _Float16* __restrict__ out, int n) {
    const int lane = threadIdx.x & 63;
    const int nwaves = gridDim.x * 4;
    int wid = (blockIdx.x * 256 + threadIdx.x) >> 6;
    const h2* hs2 = (const h2*)hs;
    const float2 bb = ((const float2*)bias)[lane];

    for (int node = wid; node < n; node += nwaves) {
        int beg = (node > 0) ? work[node - 1] : 0;
        int end = work[node];
        float dd = dinv[node];
        h2 hv = hs2[(size_t)node * 64 + lane];
        float ax = dd * (float)hv[0];
        float ay = dd * (float)hv[1];
        for (int chunk = beg; chunk < end; chunk += 64) {
            int m = end - chunk; if (m > 64) m = 64;
            int myidx = (lane < m) ? csr[chunk + lane] : 0;
            for (int j = 0; j < m; j++) {
                int s = __shfl(myidx, j);
                float ws = dinv[s];
                h2 v = hs2[(size_t)s * 64 + lane];
                ax += ws * (float)v[0];
                ay += ws * (float)v[1];
            }
        }
        float ox = fmaxf(ax * dd + bb.x, 0.f);
        float oy = fmaxf(ay * dd + bb.y, 0.f);
        h2 o; o[0] = (_Float16)ox; o[1] = (_Float16)oy;
        ((h2*)out)[(size_t)node * 64 + lane] = o;
    }
}

// ---------- pools ----------

__global__ __launch_bounds__(256) void k_pool_h(const _Float16* __restrict__ X,
                                                float* __restrict__ colsum,
                                                float* __restrict__ colmax, int n) {
    __shared__ float ls[256], lm[256];
    int c = threadIdx.x & 127;
    int grp = threadIdx.x >> 7;
    float s = 0.f, m = 0.f;
    for (int r = blockIdx.x * 2 + grp; r < n; r += gridDim.x * 2) {
        float v = (float)X[(size_t)r * FDIM + c];
        s += v;
        m = fmaxf(m, v);
    }
    ls[threadIdx.x] = s;
    lm[threadIdx.x] = m;
    __syncthreads();
    if (threadIdx.x < 128) {
        s = ls[threadIdx.x] + ls[threadIdx.x + 128];
        m = fmaxf(lm[threadIdx.x], lm[threadIdx.x + 128]);
        unsafeAtomicAdd(&colsum[c], s);
        atomicMax((int*)colmax + c, __float_as_int(m));
    }
}

__global__ __launch_bounds__(256) void k_pool_f(const float* __restrict__ X,
                                                float* __restrict__ colsum,
                                                float* __restrict__ colmax, int n) {
    __shared__ float ls[256], lm[256];
    int c = threadIdx.x & 127;
    int grp = threadIdx.x >> 7;
    float s = 0.f, m = 0.f;
    for (int r = blockIdx.x * 2 + grp; r < n; r += gridDim.x * 2) {
        float v = X[(size_t)r * FDIM + c];
        s += v;
        m = fmaxf(m, v);
    }
    ls[threadIdx.x] = s;
    lm[threadIdx.x] = m;
    __syncthreads();
    if (threadIdx.x < 128) {
        s = ls[threadIdx.x] + ls[threadIdx.x + 128];
        m = fmaxf(lm[threadIdx.x], lm[threadIdx.x + 128]);
        unsafeAtomicAdd(&colsum[c], s);
        atomicMax((int*)colmax + c, __float_as_int(m));
    }
}

__global__ __launch_bounds__(256) void k_fc(const float* __restrict__ colsum,
                                            const float* __restrict__ colmax,
                                            const float* __restrict__ fcW,
                                            const float* __restrict__ fcb,
                                            float* __restrict__ out, float invN) {
    int o = threadIdx.x;
    float acc = fcb[o];
#pragma unroll 4
    for (int k = 0; k < FDIM; k++)
        acc += colsum[k] * invN * fcW[k * 256 + o];
#pragma unroll 4
    for (int k = 0; k < FDIM; k++)
        acc += colmax[k] * fcW[(FDIM + k) * 256 + o];
    out[o] = acc;
}

// ================= fallback (round-1 atomic scatter, fp32) =================

__global__ __launch_bounds__(256) void k_initF(float* deg, float* cs, float* cm, int n) {
    int i = blockIdx.x * 256 + threadIdx.x;
    if (i < n) deg[i] = 1.0f;
    if (i < FDIM) { cs[i] = 0.0f; cm[i] = 0.0f; }
}
__global__ __launch_bounds__(256) void k_degreeF(const int* dst, float* deg, int ne) {
    int i = blockIdx.x * 256 + threadIdx.x;
    if (i < ne) unsafeAtomicAdd(&deg[dst[i]], 1.0f);
}
__global__ __launch_bounds__(256) void k_rsqrtF(float* deg, int n) {
    int i = blockIdx.x * 256 + threadIdx.x;
    if (i < n) deg[i] = 1.0f / sqrtf(deg[i]);
}
__global__ __launch_bounds__(256) void k_selfinitF(const float* H, const float* dinv,
                                                   float* acc, int n) {
    int i = blockIdx.x * 256 + threadIdx.x;
    if (i >= n * 32) return;
    int row = i >> 5;
    float s = dinv[row]; s *= s;
    float4 v = ((const float4*)H)[i];
    v.x *= s; v.y *= s; v.z *= s; v.w *= s;
    ((float4*)acc)[i] = v;
}
__global__ __launch_bounds__(256) void k_scatterF(const int* src, const int* dst,
                                                  const float* dinv, const float* H,
                                                  float* acc, int ne) {
    int e = (blockIdx.x * 256 + threadIdx.x) >> 6;
    if (e >= ne) return;
    int lane = threadIdx.x & 63;
    int s = src[e], d = dst[e];
    float w = dinv[s] * dinv[d];
    float2 v = ((const float2*)(H + (size_t)s * FDIM))[lane];
    float* ap = acc + (size_t)d * FDIM + lane * 2;
    unsafeAtomicAdd(ap, v.x * w);
    unsafeAtomicAdd(ap + 1, v.y * w);
}
__global__ __launch_bounds__(256) void k_bias_reluF(float* acc, const float* b, int n) {
    int i = blockIdx.x * 256 + threadIdx.x;
    if (i >= n * 32) return;
    float4 bb = ((const float4*)b)[i & 31];
    float4 v = ((float4*)acc)[i];
    v.x = fmaxf(v.x + bb.x, 0.f);
    v.y = fmaxf(v.y + bb.y, 0.f);
    v.z = fmaxf(v.z + bb.z, 0.f);
    v.w = fmaxf(v.w + bb.w, 0.f);
    ((float4*)acc)[i] = v;
}
__global__ __launch_bounds__(256) void k_gemm128F(const float* X, const float* W,
                                                   float* H, int n) {
    __shared__ float sW[FDIM * FDIM];
    for (int i = threadIdx.x; i < FDIM * FDIM / 4; i += 256)
        ((float4*)sW)[i] = ((const float4*)W)[i];
    __syncthreads();
    const int c = threadIdx.x & 127;
    const int half = threadIdx.x >> 7;
    for (int base = blockIdx.x * 8; base < n; base += gridDim.x * 8) {
        const int r0 = base + half * 4;
        const float* xp0 = X + (size_t)min(r0 + 0, n - 1) * FDIM;
        const float* xp1 = X + (size_t)min(r0 + 1, n - 1) * FDIM;
        const float* xp2 = X + (size_t)min(r0 + 2, n - 1) * FDIM;
        const float* xp3 = X + (size_t)min(r0 + 3, n - 1) * FDIM;
        float a0 = 0.f, a1 = 0.f, a2 = 0.f, a3 = 0.f;
#pragma unroll 8
        for (int k = 0; k < FDIM; k += 4) {
            float w0 = sW[(k + 0) * FDIM + c];
            float w1 = sW[(k + 1) * FDIM + c];
            float w2 = sW[(k + 2) * FDIM + c];
            float w3 = sW[(k + 3) * FDIM + c];
            float4 x0 = *(const float4*)(xp0 + k);
            float4 x1 = *(const float4*)(xp1 + k);
            float4 x2 = *(const float4*)(xp2 + k);
            float4 x3 = *(const float4*)(xp3 + k);
            a0 += x0.x * w0 + x0.y * w1 + x0.z * w2 + x0.w * w3;
            a1 += x1.x * w0 + x1.y * w1 + x1.z * w2 + x1.w * w3;
            a2 += x2.x * w0 + x2.y * w1 + x2.z * w2 + x2.w * w3;
            a3 += x3.x * w0 + x3.y * w1 + x3.z * w2 + x3.w * w3;
        }
        if (r0 + 0 < n) H[(size_t)(r0 + 0) * FDIM + c] = a0;
        if (r0 + 1 < n) H[(size_t)(r0 + 1) * FDIM + c] = a1;
        if (r0 + 2 < n) H[(size_t)(r0 + 2) * FDIM + c] = a2;
        if (r0 + 3 < n) H[(size_t)(r0 + 3) * FDIM + c] = a3;
    }
}

// ================= launch =================

extern "C" void kernel_launch(void* const* d_in, const int* in_sizes, int n_in,
                              void* d_out, int out_size, void* d_ws, size_t ws_size,
                              hipStream_t stream) {
    const float* X   = (const float*)d_in[0];
    const int*   ei  = (const int*)d_in[1];
    const float* W1  = (const float*)d_in[2];
    const float* b1  = (const float*)d_in[3];
    const float* W2  = (const float*)d_in[4];
    const float* b2  = (const float*)d_in[5];
    const float* fcW = (const float*)d_in[6];
    const float* fcb = (const float*)d_in[7];
    float* out = (float*)d_out;

    const int n  = in_sizes[0] / FDIM;    // 100000
    const int ne = in_sizes[1] / 2;       // 1600000
    const int* src = ei;
    const int* dst = ei + ne;

    const int gN = (n + 255) / 256;
    const int gE = (ne + 255) / 256;

    size_t need = (size_t)n * FDIM * 2 * 2 + 2 * FDIM * FDIM * 2 +
                  ((size_t)n + 2 * FDIM) * 4 + ((size_t)n * 2 + 512 + ne) * 4;

    if (ws_size >= need && gN <= 512) {
        _Float16* h    = (_Float16*)d_ws;
        _Float16* xbuf = h + (size_t)n * FDIM;
        _Float16* w1t  = xbuf + (size_t)n * FDIM;
        _Float16* w2t  = w1t + FDIM * FDIM;
        float* dinv    = (float*)(w2t + FDIM * FDIM);
        float* colsum  = dinv + n;
        float* colmax  = colsum + FDIM;
        int* counts    = (int*)(colmax + FDIM);
        int* work      = counts + n;
        int* partials  = work + n;
        int* csr       = partials + 512;

        k_zero_init<<<gN, 256, 0, stream>>>(counts, colsum, colmax, n);
        k_hist<<<gE, 256, 0, stream>>>(dst, counts, ne);
        k_dinv<<<gN, 256, 0, stream>>>(counts, dinv, n);
        k_scan1<<<gN, 256, 0, stream>>>(counts, work, partials, n);
        k_scan2<<<1, 512, 0, stream>>>(partials, gN);
        k_scan3<<<gN, 256, 0, stream>>>(work, partials, n);
        k_fill<<<gE, 256, 0, stream>>>(src, dst, work, csr, ne);
        k_transW<<<128, 256, 0, stream>>>(W1, W2, w1t, w2t);

        k_gemm_f16<float><<<512, 256, 0, stream>>>(X, w1t, h, n);
        k_aggregate<<<2048, 256, 0, stream>>>(work, csr, dinv, h, b1, xbuf, n);
        k_gemm_f16<_Float16><<<512, 256, 0, stream>>>(xbuf, w2t, h, n);
        k_aggregate<<<2048, 256, 0, stream>>>(work, csr, dinv, h, b2, xbuf, n);

        k_pool_h<<<1024, 256, 0, stream>>>(xbuf, colsum, colmax, n);
        k_fc<<<1, 256, 0, stream>>>(colsum, colmax, fcW, fcb, out, 1.0f / (float)n);
    } else {
        float* h      = (float*)d_ws;
        float* acc    = h + (size_t)n * FDIM;
        float* dinv   = acc + (size_t)n * FDIM;
        float* colsum = dinv + n;
        float* colmax = colsum + FDIM;
        const int gV = (n * 32 + 255) / 256;
        const int gS = (int)(((long long)ne * 64 + 255) / 256);

        k_initF<<<gN, 256, 0, stream>>>(dinv, colsum, colmax, n);
        k_degreeF<<<gE, 256, 0, stream>>>(dst, dinv, ne);
        k_rsqrtF<<<gN, 256, 0, stream>>>(dinv, n);

        k_gemm128F<<<1024, 256, 0, stream>>>(X, W1, h, n);
        k_selfinitF<<<gV, 256, 0, stream>>>(h, dinv, acc, n);
        k_scatterF<<<gS, 256, 0, stream>>>(src, dst, dinv, h, acc, ne);
        k_bias_reluF<<<gV, 256, 0, stream>>>(acc, b1, n);

        k_gemm128F<<<1024, 256, 0, stream>>>(acc, W2, h, n);
        k_selfinitF<<<gV, 256, 0, stream>>>(h, dinv, acc, n);
        k_scatterF<<<gS, 256, 0, stream>>>(src, dst, dinv, h, acc, ne);
        k_bias_reluF<<<gV, 256, 0, stream>>>(acc, b2, n);

        k_pool_f<<<1024, 256, 0, stream>>>(acc, colsum, colmax, n);
        k_fc<<<1, 256, 0, stream>>>(colsum, colmax, fcW, fcb, out, 1.0f / (float)n);
    }
}